// Round 1
// 554.273 us; speedup vs baseline: 1.0666x; 1.0666x over previous
//
#include <hip/hip_runtime.h>
#include <math.h>

#define N_  4
#define P_  20000
#define DIN 1024
#define K_  8
#define DH  64
#define BP  128     // patches per block
#define NT  5       // 5 col-tiles of 16: cols 0-63 = W_pre, 64-71 = centroids, 72-79 pad

typedef float  f32x4 __attribute__((ext_vector_type(4)));
typedef short  s16x8 __attribute__((ext_vector_type(8)));
typedef unsigned int u32x4 __attribute__((ext_vector_type(4)));
typedef unsigned short ushort_t;

// ws layout (float offsets). NEEDS ws_size >= 344064 bytes.
//   [0,2048)      gsum   per-(n,k,j) cluster sums
//   [2048,2080)   gcnt   per-(n,k) counts (int)
//   [2080,2088)   c2     ||centroid_k||^2
//   [4096,45056)  Bth    bf16-hi plane of B^T  [80 cols][1024 k] (ushort)
//   [45056,86016) Btl    bf16-lo plane of B^T  (ushort)

union FragU { u32x4 u; s16x8 s; };

// blocks 0..79: build B^T bf16 hi/lo planes; block 80: zero accumulators + c2
__global__ __launch_bounds__(512) void k_pre(const float* __restrict__ W_pre,
                                             const float* __restrict__ centroids,
                                             float* __restrict__ ws) {
  const int t = threadIdx.x;
  const int b = blockIdx.x;
  if (b < 80) {
    const int c = b;
    ushort_t* Bth = (ushort_t*)(ws + 4096);
    ushort_t* Btl = (ushort_t*)(ws + 45056);
    for (int d = t; d < DIN; d += 512) {
      float v = 0.f;
      if (c < 64)      v = W_pre[(size_t)d * DH + c];
      else if (c < 72) v = centroids[(size_t)(c - 64) * DIN + d];
      unsigned u = __float_as_uint(v);
      unsigned r = u + 0x7FFFu + ((u >> 16) & 1u);     // RTN to bf16
      unsigned hb = r & 0xFFFF0000u;
      float lo = v - __uint_as_float(hb);
      unsigned ul = __float_as_uint(lo);
      unsigned rl = ul + 0x7FFFu + ((ul >> 16) & 1u);
      Bth[(size_t)c * DIN + d] = (ushort_t)(hb >> 16);
      Btl[(size_t)c * DIN + d] = (ushort_t)(rl >> 16);
    }
  } else {
    int* gcnt = (int*)(ws + 2048);
    for (int i = t; i < N_ * K_ * DH; i += 512) ws[i] = 0.f;
    if (t < N_ * K_) gcnt[t] = 0;
    const int w = t >> 6, lane = t & 63;
    float s = 0.f;
    for (int d = lane; d < DIN; d += 64) {
      float v = centroids[(size_t)w * DIN + d];
      s += v * v;
    }
    for (int off = 32; off > 0; off >>= 1) s += __shfl_down(s, off, 64);
    if (lane == 0) ws[2080 + w] = s;
  }
}

// split one 8-float row-slice into truncated-bf16 hi plane + truncated lo plane
__device__ __forceinline__ void cvt_split(const f32x4 a0, const f32x4 a1,
                                          FragU& ah, FragU& al) {
  float f[8];
#pragma unroll
  for (int e = 0; e < 4; ++e) { f[e] = a0[e]; f[4 + e] = a1[e]; }
#pragma unroll
  for (int q = 0; q < 4; ++q) {
    const unsigned u0 = __float_as_uint(f[2 * q]);
    const unsigned u1 = __float_as_uint(f[2 * q + 1]);
    ah.u[q] = (u0 >> 16) | (u1 & 0xFFFF0000u);           // hi = trunc-bf16
    const float l0 = f[2 * q]     - __uint_as_float(u0 & 0xFFFF0000u);
    const float l1 = f[2 * q + 1] - __uint_as_float(u1 & 0xFFFF0000u);
    al.u[q] = (__float_as_uint(l0) >> 16) | (__float_as_uint(l1) & 0xFFFF0000u);
  }
}

// Barrier-free K-loop: each lane streams its own A-fragments straight from
// global (x has zero cross-lane reuse), B from the L2-resident bf16 planes.
// LDS holds only the epilogue xp tile -> ~38.5 KB -> 3-4 blocks/CU, and the
// whole 628-block grid is co-resident (no tail round).
__global__ __launch_bounds__(256, 3) void k_main(
    const float* __restrict__ x, const float* __restrict__ b_pre,
    float* __restrict__ out1, float* __restrict__ out2, float* __restrict__ ws) {
  __shared__ float xp[BP * 65];      // xp tile, stride 65 (bank-conflict pad)
  __shared__ float sc[BP * 9];
  __shared__ int   assign_s[BP];
  __shared__ int   cnt8[K_];

  const int t = threadIdx.x;
  const int w = t >> 6, l = t & 63;
  const int m = l & 15, q4 = l >> 4;
  const int n = blockIdx.y;
  const int p0 = blockIdx.x * BP;
  const int validP = (P_ - p0) < BP ? (P_ - p0) : BP;

  const ushort_t* Bth = (const ushort_t*)(ws + 4096);
  const ushort_t* Btl = (const ushort_t*)(ws + 45056);

  if (t < K_) cnt8[t] = 0;

  f32x4 acc[2][NT];
#pragma unroll
  for (int rg = 0; rg < 2; ++rg)
#pragma unroll
    for (int tl = 0; tl < NT; ++tl) acc[rg][tl] = (f32x4){0.f, 0.f, 0.f, 0.f};

  // per-lane A row pointers: lane (m,q4) owns rows 32w+16rg+m, k-slice q4*8..+8.
  // ks*32-float step = ks*128 B <= 3968 -> whole K-loop folds to imm offsets.
  const int r0 = p0 + 32 * w + m;
  const int r1 = r0 + 16;
  const int g0 = r0 < P_ ? r0 : P_ - 1;
  const int g1 = r1 < P_ ? r1 : P_ - 1;
  const float* xbase = x + (size_t)n * P_ * DIN + q4 * 8;
  const float* ap0 = xbase + (size_t)g0 * DIN;
  const float* ap1 = xbase + (size_t)g1 * DIN;

  const ushort_t* bhp[NT];
  const ushort_t* blp[NT];
#pragma unroll
  for (int tl = 0; tl < NT; ++tl) {
    const size_t off = (size_t)(tl * 16 + m) * DIN + q4 * 8;
    bhp[tl] = Bth + off;
    blp[tl] = Btl + off;
  }

#pragma unroll 4
  for (int ks = 0; ks < 32; ++ks) {
    const int ko = ks * 32;
    const f32x4 a00 = *(const f32x4*)(ap0 + ko);
    const f32x4 a01 = *(const f32x4*)(ap0 + ko + 4);
    const f32x4 a10 = *(const f32x4*)(ap1 + ko);
    const f32x4 a11 = *(const f32x4*)(ap1 + ko + 4);
    FragU bh[NT], bl[NT];
#pragma unroll
    for (int tl = 0; tl < NT; ++tl) {
      bh[tl].u = *(const u32x4*)(bhp[tl] + ko);
      bl[tl].u = *(const u32x4*)(blp[tl] + ko);
    }
    FragU ah0, al0, ah1, al1;
    cvt_split(a00, a01, ah0, al0);
    cvt_split(a10, a11, ah1, al1);
    // product order per acc stays hh -> hl -> lh (bitwise-identical results);
    // interleave across tl/rg so dependent MFMAs on one acc are 10 apart.
#pragma unroll
    for (int tl = 0; tl < NT; ++tl) {
      acc[0][tl] = __builtin_amdgcn_mfma_f32_16x16x32_bf16(ah0.s, bh[tl].s, acc[0][tl], 0, 0, 0);
      acc[1][tl] = __builtin_amdgcn_mfma_f32_16x16x32_bf16(ah1.s, bh[tl].s, acc[1][tl], 0, 0, 0);
    }
#pragma unroll
    for (int tl = 0; tl < NT; ++tl) {
      acc[0][tl] = __builtin_amdgcn_mfma_f32_16x16x32_bf16(ah0.s, bl[tl].s, acc[0][tl], 0, 0, 0);
      acc[1][tl] = __builtin_amdgcn_mfma_f32_16x16x32_bf16(ah1.s, bl[tl].s, acc[1][tl], 0, 0, 0);
    }
#pragma unroll
    for (int tl = 0; tl < NT; ++tl) {
      acc[0][tl] = __builtin_amdgcn_mfma_f32_16x16x32_bf16(al0.s, bh[tl].s, acc[0][tl], 0, 0, 0);
      acc[1][tl] = __builtin_amdgcn_mfma_f32_16x16x32_bf16(al1.s, bh[tl].s, acc[1][tl], 0, 0, 0);
    }
  }

  // epilogue: bias+relu, write enc_seq twice, xp -> LDS
#pragma unroll
  for (int tl = 0; tl < 4; ++tl) {
    const int col = tl * 16 + m;
    const float bb = b_pre[col];
#pragma unroll
    for (int rg = 0; rg < 2; ++rg) {
#pragma unroll
      for (int r = 0; r < 4; ++r) {
        const int row = 32 * w + 16 * rg + (q4 << 2) + r;   // C layout: row=(lane>>4)*4+reg
        float v = acc[rg][tl][r] + bb;
        v = v > 0.f ? v : 0.f;
        xp[row * 65 + col] = v;
        if (row < validP) {
          const size_t o = (((size_t)(n * P_ + p0 + row)) << 6) + col;
          out1[o] = v;
          out2[o] = v;
        }
      }
    }
  }
  // scores from col-tile 4 (cols 64-71 = centroid dots)
  if (m < K_) {
    const float cc = ws[2080 + m];
#pragma unroll
    for (int rg = 0; rg < 2; ++rg)
#pragma unroll
      for (int r = 0; r < 4; ++r) {
        const int row = 32 * w + 16 * rg + (q4 << 2) + r;
        sc[row * 9 + m] = cc - 2.f * acc[rg][4][r];
      }
  }
  __syncthreads();

  if (t < BP) {
    int a = -1;
    if (t < validP) {
      float best = 3.4e38f; int bk = 0;
#pragma unroll
      for (int k = 0; k < K_; ++k) {
        const float v = sc[t * 9 + k];
        if (v < best) { best = v; bk = k; }
      }
      a = bk;
      atomicAdd(&cnt8[bk], 1);
    }
    assign_s[t] = a;
  }
  __syncthreads();

  // per-block cluster sums -> one atomic per (k,j)
  for (int task = t; task < K_ * DH; task += 256) {
    const int k = task >> 6, j = task & 63;
    float s = 0.f;
    for (int p = 0; p < BP; ++p)
      s += (assign_s[p] == k) ? xp[p * 65 + j] : 0.f;
    if (s != 0.f) atomicAdd(&ws[(n * K_ + k) * DH + j], s);
  }
  if (t < K_ && cnt8[t] > 0) atomicAdd((int*)(ws + 2048) + n * K_ + t, cnt8[t]);
}

__global__ __launch_bounds__(256) void k_final(
    const float* __restrict__ W_a1, const float* __restrict__ b_a1,
    const float* __restrict__ W_a2, const float* __restrict__ b_a2,
    const float* __restrict__ W_out, const float* __restrict__ b_out,
    const float* __restrict__ ws, float* __restrict__ enc_cls) {
  __shared__ float xc[N_ * K_ * DH];
  __shared__ float zs[N_ * K_ * 32];
  __shared__ float wa[N_ * K_];
  __shared__ float As[N_ * K_];
  __shared__ int   cnts[N_ * K_];
  __shared__ float pooled[N_ * DH];
  const int t = threadIdx.x;
  const float* gsum = ws;
  const int* gcnt = (const int*)(ws + 2048);

  if (t < N_ * K_) cnts[t] = gcnt[t];
  __syncthreads();
  for (int i = t; i < N_ * K_ * DH; i += 256) {
    const int nk = i >> 6;
    const int c = cnts[nk];
    xc[i] = (c > 0) ? gsum[i] / (float)c : 0.f;
  }
  __syncthreads();
  // attention hidden layer: 1024 independent (nk,h) tasks across 256 threads
  for (int i = t; i < N_ * K_ * 32; i += 256) {
    const int nk = i >> 5, h = i & 31;
    float z = b_a1[h];
    for (int j = 0; j < DH; ++j) z += xc[nk * DH + j] * W_a1[j * 32 + h];
    zs[i] = tanhf(z) * W_a2[h];
  }
  __syncthreads();
  if (t < N_ * K_) {
    float a = b_a2[0];
    for (int h = 0; h < 32; ++h) a += zs[t * 32 + h];
    As[t] = (cnts[t] > 0) ? a : -100000.f;
  }
  __syncthreads();
  if (t < N_) {
    float mx = -3.4e38f;
    for (int k = 0; k < K_; ++k) mx = fmaxf(mx, As[t * K_ + k]);
    float ssum = 0.f;
    float e[K_];
    for (int k = 0; k < K_; ++k) { e[k] = expf(As[t * K_ + k] - mx); ssum += e[k]; }
    for (int k = 0; k < K_; ++k) wa[t * K_ + k] = e[k] / ssum;
  }
  __syncthreads();
  {
    const int n = t >> 6, j = t & 63;
    float s = 0.f;
    for (int k = 0; k < K_; ++k) s += xc[(n * K_ + k) * DH + j] * wa[n * K_ + k];
    pooled[t] = s;
  }
  __syncthreads();
  if (t < N_ * 32) {
    const int n = t >> 5, o = t & 31;
    float s = b_out[o];
    for (int j = 0; j < DH; ++j) s += pooled[n * DH + j] * W_out[j * 32 + o];
    enc_cls[n * 32 + o] = fmaxf(s, 0.f);
  }
}

extern "C" void kernel_launch(void* const* d_in, const int* in_sizes, int n_in,
                              void* d_out, int out_size, void* d_ws, size_t ws_size,
                              hipStream_t stream) {
  const float* x         = (const float*)d_in[0];
  const float* centroids = (const float*)d_in[1];
  const float* W_pre     = (const float*)d_in[2];
  const float* b_pre     = (const float*)d_in[3];
  const float* W_a1      = (const float*)d_in[4];
  const float* b_a1      = (const float*)d_in[5];
  const float* W_a2      = (const float*)d_in[6];
  const float* b_a2      = (const float*)d_in[7];
  const float* W_out     = (const float*)d_in[8];
  const float* b_out     = (const float*)d_in[9];

  float* out     = (float*)d_out;
  float* ws      = (float*)d_ws;
  float* enc_cls = out;
  float* out1    = out + N_ * 32;
  float* out2    = out + N_ * 32 + (size_t)N_ * P_ * DH;

  hipLaunchKernelGGL(k_pre, dim3(81), dim3(512), 0, stream, W_pre, centroids, ws);
  hipLaunchKernelGGL(k_main, dim3((P_ + BP - 1) / BP, N_), dim3(256), 0, stream,
                     x, b_pre, out1, out2, ws);
  hipLaunchKernelGGL(k_final, dim3(1), dim3(256), 0, stream,
                     W_a1, b_a1, W_a2, b_a2, W_out, b_out, ws, enc_cls);
}